// Round 1
// baseline (21182.138 us; speedup 1.0000x reference)
//
#include <hip/hip_runtime.h>

// GCN sparse conv: out = relu( sparse(adj) @ ( sparse(x) @ W ) )
// x:   COO [N_NODES x IN_DIM], 3.2M nnz
// adj: COO [N_NODES x N_NODES], 3.2M nnz
// W:   [IN_DIM=1024, OUT_DIM=256] dense f32
// out: [N_NODES=100000, OUT_DIM=256] f32

constexpr int OUT_DIM = 256;

// One 64-lane wave per nnz element (grid-stride over nnz).
// Lane l handles columns [4l, 4l+4) via float4 -> coalesced 1KB/row gather,
// then 4 float atomicAdds into the destination row.
__global__ void spmm_scatter(const int* __restrict__ rows,
                             const int* __restrict__ cols,
                             const float* __restrict__ vals,
                             const float* __restrict__ src,   // [?, OUT_DIM] gathered by cols
                             float* __restrict__ dst,         // [N_NODES, OUT_DIM] scattered by rows
                             int nnz) {
    const int lane  = threadIdx.x & 63;
    const int wave  = (int)((blockIdx.x * blockDim.x + threadIdx.x) >> 6);
    const int nwave = (int)((gridDim.x * blockDim.x) >> 6);

    for (int e = wave; e < nnz; e += nwave) {
        const int   r = rows[e];
        const int   c = cols[e];
        const float v = vals[e];

        const float4 w = reinterpret_cast<const float4*>(src + (size_t)c * OUT_DIM)[lane];

        float* d = dst + (size_t)r * OUT_DIM + (size_t)lane * 4;
        atomicAdd(d + 0, v * w.x);
        atomicAdd(d + 1, v * w.y);
        atomicAdd(d + 2, v * w.z);
        atomicAdd(d + 3, v * w.w);
    }
}

__global__ void relu_inplace_f4(float4* __restrict__ p, int n4) {
    int i      = blockIdx.x * blockDim.x + threadIdx.x;
    int stride = gridDim.x * blockDim.x;
    for (; i < n4; i += stride) {
        float4 v = p[i];
        v.x = fmaxf(v.x, 0.0f);
        v.y = fmaxf(v.y, 0.0f);
        v.z = fmaxf(v.z, 0.0f);
        v.w = fmaxf(v.w, 0.0f);
        p[i] = v;
    }
}

extern "C" void kernel_launch(void* const* d_in, const int* in_sizes, int n_in,
                              void* d_out, int out_size, void* d_ws, size_t ws_size,
                              hipStream_t stream) {
    const int*   x_rows   = (const int*)  d_in[0];
    const int*   x_cols   = (const int*)  d_in[1];
    const float* x_vals   = (const float*)d_in[2];
    const int*   adj_rows = (const int*)  d_in[3];
    const int*   adj_cols = (const int*)  d_in[4];
    const float* adj_vals = (const float*)d_in[5];
    const float* W        = (const float*)d_in[6];

    const int nnz_x   = in_sizes[0];
    const int nnz_adj = in_sizes[3];

    float* xw  = (float*)d_ws;    // [N_NODES, OUT_DIM] intermediate, 102.4 MB
    float* out = (float*)d_out;   // [N_NODES, OUT_DIM]

    const size_t row_bytes = (size_t)out_size * sizeof(float);

    // Zero accumulation buffers (async, graph-capture safe).
    hipMemsetAsync(xw,  0, row_bytes, stream);
    hipMemsetAsync(out, 0, row_bytes, stream);

    // SpMM1: xw = sparse(x) @ W
    spmm_scatter<<<8192, 256, 0, stream>>>(x_rows, x_cols, x_vals, W, xw, nnz_x);

    // SpMM2: out = sparse(adj) @ xw
    spmm_scatter<<<8192, 256, 0, stream>>>(adj_rows, adj_cols, adj_vals, xw, out, nnz_adj);

    // ReLU in place.
    relu_inplace_f4<<<2048, 256, 0, stream>>>((float4*)out, out_size / 4);
}

// Round 2
// 1635.188 us; speedup vs baseline: 12.9539x; 12.9539x over previous
//
#include <hip/hip_runtime.h>

// GCN sparse conv: out = relu( sparse(adj) @ ( sparse(x) @ W ) )
// Strategy: device-side counting sort (COO -> CSR) per sparse matrix, then
// one 64-lane wave per output row accumulating in registers (4 f32/lane = 256
// cols), single write per row. No atomics in the SpMM hot loop.

constexpr int OUT_DIM = 256;

// ---------------- counting sort: histogram -> scan -> scatter ----------------

__global__ void hist_rows(const int* __restrict__ rows, int* __restrict__ counts, int nnz) {
    int i = blockIdx.x * blockDim.x + threadIdx.x;
    int stride = gridDim.x * blockDim.x;
    for (; i < nnz; i += stride) atomicAdd(&counts[rows[i]], 1);
}

// Single-block exclusive scan of counts[n] -> offsets[n] (+offsets[n]=nnz),
// and copies the exclusive value into pos[] (scatter cursors).
__global__ void scan_exclusive(int* __restrict__ pos /* in: counts, out: cursors */,
                               int* __restrict__ offsets, int n, int nnz) {
    __shared__ int sh[1024];
    __shared__ int running;
    if (threadIdx.x == 0) running = 0;
    __syncthreads();
    for (int base = 0; base < n; base += 1024) {
        int i = base + (int)threadIdx.x;
        int c = (i < n) ? pos[i] : 0;
        sh[threadIdx.x] = c;
        __syncthreads();
        for (int off = 1; off < 1024; off <<= 1) {
            int v = sh[threadIdx.x];
            int a = (threadIdx.x >= (unsigned)off) ? sh[threadIdx.x - off] : 0;
            __syncthreads();
            sh[threadIdx.x] = v + a;
            __syncthreads();
        }
        int incl = sh[threadIdx.x];
        int excl = running + incl - c;
        if (i < n) { offsets[i] = excl; pos[i] = excl; }
        __syncthreads();
        if (threadIdx.x == 1023) running += sh[1023];
        __syncthreads();
    }
    if (threadIdx.x == 0) offsets[n] = nnz;
}

__global__ void scatter_sort(const int* __restrict__ rows, const int* __restrict__ cols,
                             const float* __restrict__ vals, int* __restrict__ pos,
                             int* __restrict__ scols, float* __restrict__ svals, int nnz) {
    int i = blockIdx.x * blockDim.x + threadIdx.x;
    int stride = gridDim.x * blockDim.x;
    for (; i < nnz; i += stride) {
        int r = rows[i];
        int p = atomicAdd(&pos[r], 1);
        scols[p] = cols[i];
        svals[p] = vals[i];
    }
}

// ---------------- CSR SpMM: one wave per row, register accumulation ----------

template <bool RELU>
__global__ void spmm_csr(const int* __restrict__ offsets,
                         const int* __restrict__ cols,
                         const float* __restrict__ vals,
                         const float* __restrict__ src,   // [?, 256] gathered by col
                         float* __restrict__ dst,         // [n, 256]
                         int n) {
    const int wave = (int)((blockIdx.x * blockDim.x + threadIdx.x) >> 6);
    const int lane = (int)(threadIdx.x & 63);
    if (wave >= n) return;

    const int start = offsets[wave];
    const int end   = offsets[wave + 1];

    const float4* __restrict__ src4 = reinterpret_cast<const float4*>(src);
    float4 acc = make_float4(0.f, 0.f, 0.f, 0.f);

    for (int e = start; e < end; ++e) {
        const int   c = cols[e];
        const float v = vals[e];
        const float4 w = src4[(size_t)c * 64 + lane];
        acc.x += v * w.x;
        acc.y += v * w.y;
        acc.z += v * w.z;
        acc.w += v * w.w;
    }
    if (RELU) {
        acc.x = fmaxf(acc.x, 0.f); acc.y = fmaxf(acc.y, 0.f);
        acc.z = fmaxf(acc.z, 0.f); acc.w = fmaxf(acc.w, 0.f);
    }
    reinterpret_cast<float4*>(dst)[(size_t)wave * 64 + lane] = acc;
}

// ---------------- fallback (atomic) path, used only if ws too small ----------

__global__ void spmm_scatter(const int* __restrict__ rows, const int* __restrict__ cols,
                             const float* __restrict__ vals, const float* __restrict__ src,
                             float* __restrict__ dst, int nnz) {
    const int lane  = threadIdx.x & 63;
    const int wave  = (int)((blockIdx.x * blockDim.x + threadIdx.x) >> 6);
    const int nwave = (int)((gridDim.x * blockDim.x) >> 6);
    for (int e = wave; e < nnz; e += nwave) {
        const int r = rows[e];
        const int c = cols[e];
        const float v = vals[e];
        const float4 w = reinterpret_cast<const float4*>(src + (size_t)c * OUT_DIM)[lane];
        float* d = dst + (size_t)r * OUT_DIM + (size_t)lane * 4;
        atomicAdd(d + 0, v * w.x);
        atomicAdd(d + 1, v * w.y);
        atomicAdd(d + 2, v * w.z);
        atomicAdd(d + 3, v * w.w);
    }
}

__global__ void relu_inplace_f4(float4* __restrict__ p, int n4) {
    int i = blockIdx.x * blockDim.x + threadIdx.x;
    int stride = gridDim.x * blockDim.x;
    for (; i < n4; i += stride) {
        float4 v = p[i];
        v.x = fmaxf(v.x, 0.f); v.y = fmaxf(v.y, 0.f);
        v.z = fmaxf(v.z, 0.f); v.w = fmaxf(v.w, 0.f);
        p[i] = v;
    }
}

// -----------------------------------------------------------------------------

extern "C" void kernel_launch(void* const* d_in, const int* in_sizes, int n_in,
                              void* d_out, int out_size, void* d_ws, size_t ws_size,
                              hipStream_t stream) {
    const int*   x_rows   = (const int*)  d_in[0];
    const int*   x_cols   = (const int*)  d_in[1];
    const float* x_vals   = (const float*)d_in[2];
    const int*   adj_rows = (const int*)  d_in[3];
    const int*   adj_cols = (const int*)  d_in[4];
    const float* adj_vals = (const float*)d_in[5];
    const float* W        = (const float*)d_in[6];

    const int nnz_x   = in_sizes[0];
    const int nnz_adj = in_sizes[3];
    const int N       = out_size / OUT_DIM;   // 100000

    float* out = (float*)d_out;
    char*  ws  = (char*)d_ws;

    // ---- workspace layout (16B-aligned) ----
    const size_t xw_bytes   = (size_t)out_size * sizeof(float);          // 102.4 MB
    const size_t off_bytes  = (((size_t)(N + 1) * 4) + 15) & ~(size_t)15;
    const size_t pos_bytes  = (((size_t)N * 4) + 15) & ~(size_t)15;
    const int    nnz_max    = (nnz_x > nnz_adj) ? nnz_x : nnz_adj;
    const size_t col_bytes  = (((size_t)nnz_max * 4) + 15) & ~(size_t)15;
    const size_t val_bytes  = col_bytes;
    const size_t need       = xw_bytes + off_bytes + pos_bytes + col_bytes + val_bytes;

    float* xw = (float*)ws;

    if (ws_size < need) {
        // Fallback: atomic scatter path (requires only xw).
        hipMemsetAsync(xw,  0, xw_bytes, stream);
        hipMemsetAsync(out, 0, xw_bytes, stream);
        spmm_scatter<<<8192, 256, 0, stream>>>(x_rows, x_cols, x_vals, W, xw, nnz_x);
        spmm_scatter<<<8192, 256, 0, stream>>>(adj_rows, adj_cols, adj_vals, xw, out, nnz_adj);
        relu_inplace_f4<<<2048, 256, 0, stream>>>((float4*)out, out_size / 4);
        return;
    }

    int*   offsets = (int*)  (ws + xw_bytes);
    int*   pos     = (int*)  (ws + xw_bytes + off_bytes);
    int*   scols   = (int*)  (ws + xw_bytes + off_bytes + pos_bytes);
    float* svals   = (float*)(ws + xw_bytes + off_bytes + pos_bytes + col_bytes);

    const int spmm_blocks = (int)(((size_t)N * 64 + 255) / 256);

    // ---- SpMM1: xw = sparse(x) @ W ----
    hipMemsetAsync(pos, 0, (size_t)N * 4, stream);
    hist_rows<<<2048, 256, 0, stream>>>(x_rows, pos, nnz_x);
    scan_exclusive<<<1, 1024, 0, stream>>>(pos, offsets, N, nnz_x);
    scatter_sort<<<2048, 256, 0, stream>>>(x_rows, x_cols, x_vals, pos, scols, svals, nnz_x);
    spmm_csr<false><<<spmm_blocks, 256, 0, stream>>>(offsets, scols, svals, W, xw, N);

    // ---- SpMM2: out = relu( sparse(adj) @ xw )  (reuse sort buffers) ----
    hipMemsetAsync(pos, 0, (size_t)N * 4, stream);
    hist_rows<<<2048, 256, 0, stream>>>(adj_rows, pos, nnz_adj);
    scan_exclusive<<<1, 1024, 0, stream>>>(pos, offsets, N, nnz_adj);
    scatter_sort<<<2048, 256, 0, stream>>>(adj_rows, adj_cols, adj_vals, pos, scols, svals, nnz_adj);
    spmm_csr<true><<<spmm_blocks, 256, 0, stream>>>(offsets, scols, svals, xw, out, N);
}

// Round 3
// 1171.521 us; speedup vs baseline: 18.0809x; 1.3958x over previous
//
#include <hip/hip_runtime.h>

// GCN sparse conv: out = relu( sparse(adj) @ ( sparse(x) @ W ) )
// Pipeline: COO->CSR counting sort (hist -> hierarchical scan -> packed
// scatter) for both matrices, then CSR SpMM with one 64-lane wave per row,
// register accumulation, no atomics in hot loops. Intermediate xw stored bf16
// (halves the random-gather traffic of SpMM2; 51 MB -> fully L3-resident).

constexpr int OUT_DIM = 256;

static __device__ __forceinline__ unsigned short f2bf(float f) {
    unsigned u = __float_as_uint(f);
    unsigned r = (u + 0x7FFFu + ((u >> 16) & 1u)) >> 16;   // round-nearest-even
    return (unsigned short)r;
}

// ---------------- counting sort ----------------

__global__ void hist_rows(const int* __restrict__ rows, int* __restrict__ counts, int nnz) {
    int i = blockIdx.x * blockDim.x + threadIdx.x;
    int stride = gridDim.x * blockDim.x;
    for (; i < nnz; i += stride) atomicAdd(&counts[rows[i]], 1);
}

// Per-1024-chunk sums. 256 threads/block, 4 elements/thread.
__global__ void block_sums(const int* __restrict__ counts, int n, int* __restrict__ bsum) {
    __shared__ int sh[256];
    const int b = blockIdx.x, t = threadIdx.x;
    const int idx = b * 1024 + t * 4;
    int s = 0;
    if (idx + 3 < n) {
        int4 v = *reinterpret_cast<const int4*>(counts + idx);
        s = v.x + v.y + v.z + v.w;
    } else {
        for (int k = 0; k < 4; ++k) if (idx + k < n) s += counts[idx + k];
    }
    sh[t] = s;
    __syncthreads();
    for (int off = 128; off > 0; off >>= 1) {
        if (t < off) sh[t] += sh[t + off];
        __syncthreads();
    }
    if (t == 0) bsum[b] = sh[0];
}

// Single block: exclusive scan of nb (<=1024) block sums, in place.
__global__ void scan_bsums(int* __restrict__ bsum, int nb) {
    __shared__ int sh[1024];
    const int t = threadIdx.x;
    const int v = (t < nb) ? bsum[t] : 0;
    sh[t] = v;
    __syncthreads();
    for (int off = 1; off < 1024; off <<= 1) {
        int cur = sh[t];
        int a = (t >= off) ? sh[t - off] : 0;
        __syncthreads();
        sh[t] = cur + a;
        __syncthreads();
    }
    if (t < nb) bsum[t] = sh[t] - v;   // exclusive
}

// Per-chunk exclusive scan + add chunk offset; writes offsets[] and cursor pos[].
// counts and pos may alias (read-before-write within the same block range).
__global__ void scan_finalize(const int* __restrict__ counts, const int* __restrict__ boff,
                              int* __restrict__ offsets, int* __restrict__ pos,
                              int n, int nnz) {
    __shared__ int sh[256];
    const int b = blockIdx.x, t = threadIdx.x;
    const int idx = b * 1024 + t * 4;
    int c0 = 0, c1 = 0, c2 = 0, c3 = 0;
    if (idx + 3 < n) {
        int4 v = *reinterpret_cast<const int4*>(counts + idx);
        c0 = v.x; c1 = v.y; c2 = v.z; c3 = v.w;
    } else {
        if (idx + 0 < n) c0 = counts[idx + 0];
        if (idx + 1 < n) c1 = counts[idx + 1];
        if (idx + 2 < n) c2 = counts[idx + 2];
        if (idx + 3 < n) c3 = counts[idx + 3];
    }
    const int tsum = c0 + c1 + c2 + c3;
    sh[t] = tsum;
    __syncthreads();
    for (int off = 1; off < 256; off <<= 1) {
        int cur = sh[t];
        int a = (t >= off) ? sh[t - off] : 0;
        __syncthreads();
        sh[t] = cur + a;
        __syncthreads();
    }
    const int base = boff[b] + sh[t] - tsum;
    const int o0 = base, o1 = o0 + c0, o2 = o1 + c1, o3 = o2 + c2;
    if (idx + 3 < n) {
        *reinterpret_cast<int4*>(offsets + idx) = make_int4(o0, o1, o2, o3);
        *reinterpret_cast<int4*>(pos + idx)     = make_int4(o0, o1, o2, o3);
    } else {
        if (idx + 0 < n) { offsets[idx + 0] = o0; pos[idx + 0] = o0; }
        if (idx + 1 < n) { offsets[idx + 1] = o1; pos[idx + 1] = o1; }
        if (idx + 2 < n) { offsets[idx + 2] = o2; pos[idx + 2] = o2; }
        if (idx + 3 < n) { offsets[idx + 3] = o3; pos[idx + 3] = o3; }
    }
    if (b == 0 && t == 0) offsets[n] = nnz;
}

// Scatter edges into CSR order as packed uint2{col, val_bits}: one 8B write.
__global__ void scatter_pack(const int* __restrict__ rows, const int* __restrict__ cols,
                             const float* __restrict__ vals, int* __restrict__ pos,
                             uint2* __restrict__ edges, int nnz) {
    int i = blockIdx.x * blockDim.x + threadIdx.x;
    int stride = gridDim.x * blockDim.x;
    for (; i < nnz; i += stride) {
        int p = atomicAdd(&pos[rows[i]], 1);
        edges[p] = make_uint2((unsigned)cols[i], __float_as_uint(vals[i]));
    }
}

// ---------------- SpMM1: xw(bf16) = sparse(x) @ W(f32) ----------------
// One wave per row; lane l owns cols [4l,4l+4): gathers float4 from W, packs
// 4 bf16 (8B) on store.
__global__ void spmm1(const int* __restrict__ offsets, const uint2* __restrict__ edges,
                      const float* __restrict__ W, uint2* __restrict__ xw, int n) {
    const int wave = (int)((blockIdx.x * blockDim.x + threadIdx.x) >> 6);
    const int lane = (int)(threadIdx.x & 63);
    if (wave >= n) return;
    const int s = offsets[wave], e = offsets[wave + 1];
    const float4* __restrict__ W4 = reinterpret_cast<const float4*>(W);

    float4 acc = make_float4(0.f, 0.f, 0.f, 0.f);
    int i = s;
    for (; i + 1 < e; i += 2) {
        const uint2 e0 = edges[i], e1 = edges[i + 1];
        const float4 w0 = W4[(size_t)e0.x * 64 + lane];
        const float4 w1 = W4[(size_t)e1.x * 64 + lane];
        const float v0 = __uint_as_float(e0.y), v1 = __uint_as_float(e1.y);
        acc.x += v0 * w0.x + v1 * w1.x;
        acc.y += v0 * w0.y + v1 * w1.y;
        acc.z += v0 * w0.z + v1 * w1.z;
        acc.w += v0 * w0.w + v1 * w1.w;
    }
    if (i < e) {
        const uint2 e0 = edges[i];
        const float4 w0 = W4[(size_t)e0.x * 64 + lane];
        const float v0 = __uint_as_float(e0.y);
        acc.x += v0 * w0.x; acc.y += v0 * w0.y;
        acc.z += v0 * w0.z; acc.w += v0 * w0.w;
    }
    const unsigned lo = (unsigned)f2bf(acc.x) | ((unsigned)f2bf(acc.y) << 16);
    const unsigned hi = (unsigned)f2bf(acc.z) | ((unsigned)f2bf(acc.w) << 16);
    xw[(size_t)wave * 64 + lane] = make_uint2(lo, hi);
}

// ---------------- SpMM2: out(f32) = relu( sparse(adj) @ xw(bf16) ) ----------
// Lane gathers 8B (4 bf16) per edge.
__global__ void spmm2(const int* __restrict__ offsets, const uint2* __restrict__ edges,
                      const uint2* __restrict__ xw, float4* __restrict__ out, int n) {
    const int wave = (int)((blockIdx.x * blockDim.x + threadIdx.x) >> 6);
    const int lane = (int)(threadIdx.x & 63);
    if (wave >= n) return;
    const int s = offsets[wave], e = offsets[wave + 1];

    float4 acc = make_float4(0.f, 0.f, 0.f, 0.f);
    int i = s;
    for (; i + 1 < e; i += 2) {
        const uint2 e0 = edges[i], e1 = edges[i + 1];
        const uint2 g0 = xw[(size_t)e0.x * 64 + lane];
        const uint2 g1 = xw[(size_t)e1.x * 64 + lane];
        const float v0 = __uint_as_float(e0.y), v1 = __uint_as_float(e1.y);
        acc.x += v0 * __uint_as_float(g0.x << 16)          + v1 * __uint_as_float(g1.x << 16);
        acc.y += v0 * __uint_as_float(g0.x & 0xFFFF0000u)  + v1 * __uint_as_float(g1.x & 0xFFFF0000u);
        acc.z += v0 * __uint_as_float(g0.y << 16)          + v1 * __uint_as_float(g1.y << 16);
        acc.w += v0 * __uint_as_float(g0.y & 0xFFFF0000u)  + v1 * __uint_as_float(g1.y & 0xFFFF0000u);
    }
    if (i < e) {
        const uint2 e0 = edges[i];
        const uint2 g0 = xw[(size_t)e0.x * 64 + lane];
        const float v0 = __uint_as_float(e0.y);
        acc.x += v0 * __uint_as_float(g0.x << 16);
        acc.y += v0 * __uint_as_float(g0.x & 0xFFFF0000u);
        acc.z += v0 * __uint_as_float(g0.y << 16);
        acc.w += v0 * __uint_as_float(g0.y & 0xFFFF0000u);
    }
    acc.x = fmaxf(acc.x, 0.f); acc.y = fmaxf(acc.y, 0.f);
    acc.z = fmaxf(acc.z, 0.f); acc.w = fmaxf(acc.w, 0.f);
    out[(size_t)wave * 64 + lane] = acc;
}

// ---------------- fallback (atomic) path ----------------

__global__ void spmm_scatter(const int* __restrict__ rows, const int* __restrict__ cols,
                             const float* __restrict__ vals, const float* __restrict__ src,
                             float* __restrict__ dst, int nnz) {
    const int lane  = threadIdx.x & 63;
    const int wave  = (int)((blockIdx.x * blockDim.x + threadIdx.x) >> 6);
    const int nwave = (int)((gridDim.x * blockDim.x) >> 6);
    for (int e = wave; e < nnz; e += nwave) {
        const int r = rows[e];
        const int c = cols[e];
        const float v = vals[e];
        const float4 w = reinterpret_cast<const float4*>(src + (size_t)c * OUT_DIM)[lane];
        float* d = dst + (size_t)r * OUT_DIM + (size_t)lane * 4;
        atomicAdd(d + 0, v * w.x);
        atomicAdd(d + 1, v * w.y);
        atomicAdd(d + 2, v * w.z);
        atomicAdd(d + 3, v * w.w);
    }
}

__global__ void relu_inplace_f4(float4* __restrict__ p, int n4) {
    int i = blockIdx.x * blockDim.x + threadIdx.x;
    int stride = gridDim.x * blockDim.x;
    for (; i < n4; i += stride) {
        float4 v = p[i];
        v.x = fmaxf(v.x, 0.f); v.y = fmaxf(v.y, 0.f);
        v.z = fmaxf(v.z, 0.f); v.w = fmaxf(v.w, 0.f);
        p[i] = v;
    }
}

// -----------------------------------------------------------------------------

static inline size_t al16(size_t x) { return (x + 15) & ~(size_t)15; }

extern "C" void kernel_launch(void* const* d_in, const int* in_sizes, int n_in,
                              void* d_out, int out_size, void* d_ws, size_t ws_size,
                              hipStream_t stream) {
    const int*   x_rows   = (const int*)  d_in[0];
    const int*   x_cols   = (const int*)  d_in[1];
    const float* x_vals   = (const float*)d_in[2];
    const int*   adj_rows = (const int*)  d_in[3];
    const int*   adj_cols = (const int*)  d_in[4];
    const float* adj_vals = (const float*)d_in[5];
    const float* W        = (const float*)d_in[6];

    const int nnz_x   = in_sizes[0];
    const int nnz_adj = in_sizes[3];
    const int N       = out_size / OUT_DIM;          // 100000
    const int nb      = (N + 1023) / 1024;           // scan chunks

    float* out = (float*)d_out;
    char*  ws  = (char*)d_ws;

    // ---- workspace layout ----
    const size_t xw_bytes   = al16((size_t)N * OUT_DIM * 2);        // bf16 xw
    const size_t off_bytes  = al16((size_t)(N + 1) * 4);
    const size_t pos_bytes  = al16((size_t)N * 4);
    const size_t bsum_bytes = al16((size_t)nb * 4);
    const size_t ex_bytes   = al16((size_t)nnz_x * 8);
    const size_t ea_bytes   = al16((size_t)nnz_adj * 8);
    const size_t need = xw_bytes + 2 * off_bytes + 2 * pos_bytes + 2 * bsum_bytes
                      + ex_bytes + ea_bytes;

    if (ws_size < need) {
        // Fallback: atomic scatter path (f32 xw in ws).
        float* xwf = (float*)ws;
        hipMemsetAsync(xwf, 0, (size_t)out_size * 4, stream);
        hipMemsetAsync(out, 0, (size_t)out_size * 4, stream);
        spmm_scatter<<<8192, 256, 0, stream>>>(x_rows, x_cols, x_vals, W, xwf, nnz_x);
        spmm_scatter<<<8192, 256, 0, stream>>>(adj_rows, adj_cols, adj_vals, xwf, out, nnz_adj);
        relu_inplace_f4<<<2048, 256, 0, stream>>>((float4*)out, out_size / 4);
        return;
    }

    char* p = ws;
    uint2* xw      = (uint2*)p;            p += xw_bytes;
    int*   off_x   = (int*)p;              p += off_bytes;
    int*   off_a   = (int*)p;              p += off_bytes;
    int*   pos_x   = (int*)p;              p += pos_bytes;
    int*   pos_a   = (int*)p;              p += pos_bytes;   // contiguous with pos_x
    int*   bsum_x  = (int*)p;              p += bsum_bytes;
    int*   bsum_a  = (int*)p;              p += bsum_bytes;
    uint2* edges_x = (uint2*)p;            p += ex_bytes;
    uint2* edges_a = (uint2*)p;            p += ea_bytes;

    const int spmm_blocks = (N + 3) / 4;   // 4 waves / 256-thread block

    // ---- build CSR for x ----
    hipMemsetAsync(pos_x, 0, (size_t)N * 4, stream);
    hipMemsetAsync(pos_a, 0, (size_t)N * 4, stream);
    hist_rows<<<2048, 256, 0, stream>>>(x_rows, pos_x, nnz_x);
    hist_rows<<<2048, 256, 0, stream>>>(adj_rows, pos_a, nnz_adj);
    block_sums<<<nb, 256, 0, stream>>>(pos_x, N, bsum_x);
    block_sums<<<nb, 256, 0, stream>>>(pos_a, N, bsum_a);
    scan_bsums<<<1, 1024, 0, stream>>>(bsum_x, nb);
    scan_bsums<<<1, 1024, 0, stream>>>(bsum_a, nb);
    scan_finalize<<<nb, 256, 0, stream>>>(pos_x, bsum_x, off_x, pos_x, N, nnz_x);
    scan_finalize<<<nb, 256, 0, stream>>>(pos_a, bsum_a, off_a, pos_a, N, nnz_adj);
    scatter_pack<<<2048, 256, 0, stream>>>(x_rows, x_cols, x_vals, pos_x, edges_x, nnz_x);
    scatter_pack<<<2048, 256, 0, stream>>>(adj_rows, adj_cols, adj_vals, pos_a, edges_a, nnz_adj);

    // ---- SpMM1: xw = sparse(x) @ W  (bf16 out) ----
    spmm1<<<spmm_blocks, 256, 0, stream>>>(off_x, edges_x, W, xw, N);

    // ---- SpMM2: out = relu( sparse(adj) @ xw ) ----
    spmm2<<<spmm_blocks, 256, 0, stream>>>(off_a, edges_a, xw, (float4*)out, N);
}